// Round 10
// baseline (2868.220 us; speedup 1.0000x reference)
//
#include <hip/hip_runtime.h>
#include <cmath>

#define B 64
#define S 4096
#define NI 16
#define H 128
#define F 144   // H + NI
#define CH 16   // timesteps per chunk (gi tile, handoff, flush)
#define NCH (S / CH)
#define GIP 129 // padded gi row

typedef _Float16 h2   __attribute__((ext_vector_type(2)));
typedef _Float16 h8   __attribute__((ext_vector_type(8)));
typedef float    f4v  __attribute__((ext_vector_type(4)));
typedef unsigned long long u64;
typedef u64 u64x2 __attribute__((ext_vector_type(2)));

__device__ __forceinline__ float rcp_fast(float x) { return __builtin_amdgcn_rcpf(x); }
__device__ __forceinline__ float sigf(float x) {
    return rcp_fast(1.0f + __expf(-x));
}
// tanh(x) = 2*sigmoid(2x) - 1
__device__ __forceinline__ float tanh_fast(float x) {
    const float e = __expf(-2.0f * x);
    return fmaf(2.0f, rcp_fast(1.0f + e), -1.0f);
}
__device__ __forceinline__ h2 cvt2(float a, float b) {
    h2 r; r[0] = (_Float16)a; r[1] = (_Float16)b; return r;
}
// convert 8 consecutive fp32 -> 4 packed half2 regs
__device__ __forceinline__ void cvt8(const float* p, h2* w) {
    const float4 f0 = ((const float4*)p)[0];
    const float4 f1 = ((const float4*)p)[1];
    w[0] = cvt2(f0.x, f0.y); w[1] = cvt2(f0.z, f0.w);
    w[2] = cvt2(f1.x, f1.y); w[3] = cvt2(f1.z, f1.w);
}
// convert 8 consecutive fp32 -> h8
__device__ __forceinline__ h8 cvt8v(const float* p) {
    const float4 f0 = ((const float4*)p)[0];
    const float4 f1 = ((const float4*)p)[1];
    h8 r;
    r[0] = (_Float16)f0.x; r[1] = (_Float16)f0.y;
    r[2] = (_Float16)f0.z; r[3] = (_Float16)f0.w;
    r[4] = (_Float16)f1.x; r[5] = (_Float16)f1.y;
    r[6] = (_Float16)f1.z; r[7] = (_Float16)f1.w;
    return r;
}
__device__ __forceinline__ void pin_h2(h2& v) {
    int t = __builtin_bit_cast(int, v);
    asm volatile("" : "+v"(t));
    v = __builtin_bit_cast(h2, t);
}
__device__ __forceinline__ void pin_f(float& v) { asm volatile("" : "+v"(v)); }
__device__ __forceinline__ void pin_h8(h8& v) {
    u64x2 t = __builtin_bit_cast(u64x2, v);
    u64 a = t[0], b = t[1];
    asm volatile("" : "+v"(a), "+v"(b));
    t[0] = a; t[1] = b;
    v = __builtin_bit_cast(h8, t);
}
__device__ __forceinline__ f4v mfma16(h8 a, h8 b, f4v c) {
    return __builtin_amdgcn_mfma_f32_16x16x32_f16(a, b, c, 0, 0, 0);
}

// ---- intra-block monotonic-counter sync (LDS, workgroup scope) ----
__device__ __forceinline__ void poll_ge(int* p, int v) {
    int spins = 0;
    while (__hip_atomic_load(p, __ATOMIC_ACQUIRE, __HIP_MEMORY_SCOPE_WORKGROUP) < v) {
        __builtin_amdgcn_s_sleep(1);
        if (++spins > (1 << 20)) break;   // safety: wrong answer, not a hang
    }
}
__device__ __forceinline__ void publish(int* p, int v) {
    __hip_atomic_store(p, v, __ATOMIC_RELEASE, __HIP_MEMORY_SCOPE_WORKGROUP);
}

// ---- cross-XCD-safe handoff primitives (agent scope) ----
__device__ __forceinline__ void store_y0(void* p, uint2 v) {
    __hip_atomic_store((u64*)p, __builtin_bit_cast(u64, v),
                       __ATOMIC_RELAXED, __HIP_MEMORY_SCOPE_AGENT);
}
__device__ __forceinline__ h8 load_y0_h8(const _Float16* p) {
    u64x2 v;
    v[0] = __hip_atomic_load((const u64*)p,     __ATOMIC_RELAXED, __HIP_MEMORY_SCOPE_AGENT);
    v[1] = __hip_atomic_load((const u64*)p + 1, __ATOMIC_RELAXED, __HIP_MEMORY_SCOPE_AGENT);
    return __builtin_bit_cast(h8, v);
}
__device__ __forceinline__ void wait_flag(int* f) {
    int spins = 0;
    while (__hip_atomic_load(f, __ATOMIC_ACQUIRE, __HIP_MEMORY_SCOPE_AGENT) == 0) {
        __builtin_amdgcn_s_sleep(8);
        if (++spins > (1 << 17)) break;
    }
}
__device__ __forceinline__ void post_flag(int* f) {
    __hip_atomic_store(f, 1, __ATOMIC_RELEASE, __HIP_MEMORY_SCOPE_AGENT);
}

// ---------------------------------------------------------------------------
// Barrier-free GRU. 128 blocks x 256 threads (4 waves).
// blockIdx even = layer-0 block, odd = layer-1 block (batch = blockIdx>>1);
// inter-block y0 handoff via agent-scope stores + flags (r3-proven).
// Per block:
//   waves 0-1: recurrence. 1 unit/lane, FULL-K weights in VGPRs (192 h2/lane)
//     -> no cross-lane reduce. Per step: 192 fdot2, gates, write own h half,
//     pairwise counter handshake (release/acquire), broadcast-read h row.
//     NO __syncthreads, NO global access in the loop.
//   waves 2-3: helpers (chunk-granular): gi = in . W_ih^T + bias via MFMA
//     (L0: x from global, K=16; L1: y0 from global after flag, K=128),
//     flush of the out ring to global, flag posting. Synced to rec waves by
//     monotonic LDS counters only.
// Ring-safety: depth-2 sH ping-pong is race-free because each wave's read of
// h[t] precedes (program order) its write of h[t+2], which the partner's
// cnt>=t+2 poll gates. Helper iteration c is gated on rec cnt>=16(c-1), and
// rec's giDone>=c+1 poll subsumes the flush gate (helper program order).
// ---------------------------------------------------------------------------
__global__ __launch_bounds__(256, 1)
void gru_poll(const float* __restrict__ x,
              const float* __restrict__ w_ih0, const float* __restrict__ w_hh0,
              const float* __restrict__ b_ih0, const float* __restrict__ b_hh0,
              const float* __restrict__ w_ih1, const float* __restrict__ w_hh1,
              const float* __restrict__ b_ih1, const float* __restrict__ b_hh1,
              _Float16* __restrict__ hbuf, int* __restrict__ flags)
{
    __shared__ __align__(16) _Float16 sH[2][H];            // h ping-pong
    __shared__ __align__(16) float    sGi[2][CH][3][GIP];  // 49.5 KB
    __shared__ __align__(16) _Float16 sO[2][CH][H];        // out ring (y0/h1)
    __shared__ int sCnt[2];      // rec step counters
    __shared__ int sGiDone[2];   // per-helper-wave gi chunks done
    __shared__ int sFlush[2];    // per-helper-wave chunks flushed

    const int tid  = threadIdx.x;
    const int wave = tid >> 6;
    const int lane = tid & 63;
    const int b    = blockIdx.x >> 1;
    const bool producer = (blockIdx.x & 1) == 0;

    _Float16* yb = hbuf + (size_t)b * S * H;   // y0 stream (L1: h1 out in place)
    int*      fb = flags + b * NCH;

    if (tid == 0) {
        sCnt[0] = 0; sCnt[1] = 0;
        sGiDone[0] = 0; sGiDone[1] = 0;
        sFlush[0] = 0; sFlush[1] = 0;
    }
    __syncthreads();   // once, before the loop

    if (wave < 2) {
        // ================= recurrence pair =================
        const int j = 64 * wave + lane;            // unit 0..127
        const float* Whh = producer ? w_hh0 : w_hh1;
        const float* Bhh = producer ? b_hh0 : b_hh1;

        h2 w[192];   // [0..63] r, [64..127] z, [128..191] hn — full K
#pragma unroll
        for (int g = 0; g < 3; g++)
#pragma unroll
            for (int i = 0; i < 16; i++)
                cvt8(Whh + (size_t)(g * H + j) * H + 8 * i, &w[g * 64 + 4 * i]);
        float b_hn = Bhh[2 * H + j];
#pragma unroll
        for (int i = 0; i < 192; i++) pin_h2(w[i]);
        pin_f(b_hn);

        float4 hv[16];
#pragma unroll
        for (int i = 0; i < 16; i++) hv[i] = make_float4(0.f, 0.f, 0.f, 0.f);
        float hprev = 0.0f;

        int* me = &sCnt[wave];
        int* ot = &sCnt[wave ^ 1];

        for (int t = 0; t < S; t++) {
            const int c = t >> 4, tw = t & 15;
            if (tw == 0) {          // gi chunk ready? (subsumes flush gate)
                poll_ge(&sGiDone[0], c + 1);
                poll_ge(&sGiDone[1], c + 1);
            }
            const float gr = sGi[c & 1][tw][0][j];
            const float gz = sGi[c & 1][tw][1][j];
            const float gn = sGi[c & 1][tw][2][j];

            float ar0 = 0.f, az0 = 0.f, an0 = 0.f;
            float ar1 = 0.f, az1 = 0.f, an1 = 0.f;
#pragma unroll
            for (int i = 0; i < 8; i++) {
                const float4 q = hv[i];
                const h2 p0 = __builtin_bit_cast(h2, q.x);
                const h2 p1 = __builtin_bit_cast(h2, q.y);
                const h2 p2 = __builtin_bit_cast(h2, q.z);
                const h2 p3 = __builtin_bit_cast(h2, q.w);
                ar0 = __builtin_amdgcn_fdot2(p0, w[4*i+0],     ar0, false);
                ar0 = __builtin_amdgcn_fdot2(p1, w[4*i+1],     ar0, false);
                ar0 = __builtin_amdgcn_fdot2(p2, w[4*i+2],     ar0, false);
                ar0 = __builtin_amdgcn_fdot2(p3, w[4*i+3],     ar0, false);
                az0 = __builtin_amdgcn_fdot2(p0, w[64+4*i+0],  az0, false);
                az0 = __builtin_amdgcn_fdot2(p1, w[64+4*i+1],  az0, false);
                az0 = __builtin_amdgcn_fdot2(p2, w[64+4*i+2],  az0, false);
                az0 = __builtin_amdgcn_fdot2(p3, w[64+4*i+3],  az0, false);
                an0 = __builtin_amdgcn_fdot2(p0, w[128+4*i+0], an0, false);
                an0 = __builtin_amdgcn_fdot2(p1, w[128+4*i+1], an0, false);
                an0 = __builtin_amdgcn_fdot2(p2, w[128+4*i+2], an0, false);
                an0 = __builtin_amdgcn_fdot2(p3, w[128+4*i+3], an0, false);
            }
#pragma unroll
            for (int i = 8; i < 16; i++) {
                const float4 q = hv[i];
                const h2 p0 = __builtin_bit_cast(h2, q.x);
                const h2 p1 = __builtin_bit_cast(h2, q.y);
                const h2 p2 = __builtin_bit_cast(h2, q.z);
                const h2 p3 = __builtin_bit_cast(h2, q.w);
                ar1 = __builtin_amdgcn_fdot2(p0, w[4*i+0],     ar1, false);
                ar1 = __builtin_amdgcn_fdot2(p1, w[4*i+1],     ar1, false);
                ar1 = __builtin_amdgcn_fdot2(p2, w[4*i+2],     ar1, false);
                ar1 = __builtin_amdgcn_fdot2(p3, w[4*i+3],     ar1, false);
                az1 = __builtin_amdgcn_fdot2(p0, w[64+4*i+0],  az1, false);
                az1 = __builtin_amdgcn_fdot2(p1, w[64+4*i+1],  az1, false);
                az1 = __builtin_amdgcn_fdot2(p2, w[64+4*i+2],  az1, false);
                az1 = __builtin_amdgcn_fdot2(p3, w[64+4*i+3],  az1, false);
                an1 = __builtin_amdgcn_fdot2(p0, w[128+4*i+0], an1, false);
                an1 = __builtin_amdgcn_fdot2(p1, w[128+4*i+1], an1, false);
                an1 = __builtin_amdgcn_fdot2(p2, w[128+4*i+2], an1, false);
                an1 = __builtin_amdgcn_fdot2(p3, w[128+4*i+3], an1, false);
            }
            const float r  = sigf(ar0 + ar1 + gr);
            const float z  = sigf(az0 + az1 + gz);
            const float n  = tanh_fast(gn + r * (an0 + an1 + b_hn));
            const float hn = n + z * (hprev - n);
            hprev = hn;

            sH[t & 1][j]     = (_Float16)hn;
            sO[c & 1][tw][j] = (_Float16)hn;
            publish(me, t + 1);          // release: orders the two ds_writes
            poll_ge(ot, t + 1);          // acquire: partner's half visible
            const float4* hb = (const float4*)&sH[t & 1][0];
#pragma unroll
            for (int i = 0; i < 16; i++) hv[i] = hb[i];
        }
    } else {
        // ================= helper pair (chunk-granular) =================
        const int hw = wave - 2;           // 0 or 1
        const int nl = lane & 15;          // A row (timestep) / B col n
        const int q  = lane >> 4;          // k-group / C row group
        const float* xb = x + (size_t)b * S * NI;

        h8 Bf4[12][4];   // consumer: W_ih1 fragments (K=128)
        h8 Bf1[12];      // producer: W_ih0 fragments (K=16)
        float bias[12];
#pragma unroll
        for (int tt = 0; tt < 12; tt++) {
            const int n = 16 * (hw * 12 + tt) + nl;
            if (producer) {
                if (q < 2) Bf1[tt] = cvt8v(w_ih0 + (size_t)n * NI + 8 * q);
                else { h8 zz = {}; Bf1[tt] = zz; }
                pin_h8(Bf1[tt]);
                bias[tt] = b_ih0[n] + (n < 2 * H ? b_hh0[n] : 0.0f);
            } else {
                const float* wr = w_ih1 + (size_t)n * H;
#pragma unroll
                for (int kc = 0; kc < 4; kc++) {
                    Bf4[tt][kc] = cvt8v(wr + 32 * kc + 8 * q);
                    pin_h8(Bf4[tt][kc]);
                }
                bias[tt] = b_ih1[n] + (n < 2 * H ? b_hh1[n] : 0.0f);
            }
            pin_f(bias[tt]);
        }

        for (int c = 0; c < NCH; c++) {
            if (c >= 2) {
                // rec finished chunk c-2: sO[c&1] complete, sGi[c&1] consumed
                poll_ge(&sCnt[0], 16 * (c - 1));
                poll_ge(&sCnt[1], 16 * (c - 1));
                const int k = c - 2;
                const uint2* src = (const uint2*)&sO[c & 1][0][0];
#pragma unroll
                for (int e = 0; e < 4; e++) {
                    const int idx = hw * 256 + 64 * e + lane;
                    const uint2 v = src[idx];
                    if (producer)
                        store_y0((char*)(yb + (size_t)k * CH * H) + 8 * idx, v);
                    else
                        *(uint2*)((char*)(yb + (size_t)k * CH * H) + 8 * idx) = v;
                }
                if (producer) {
                    publish(&sFlush[hw], c - 1);   // release waits own vmcnt
                    if (hw == 0) {
                        poll_ge(&sFlush[1], c - 1);
                        if (lane == 0) post_flag(fb + k);
                    }
                }
            }
            // gi for chunk c
            f4v accs[12];
#pragma unroll
            for (int tt = 0; tt < 12; tt++) { f4v zz = {0.f,0.f,0.f,0.f}; accs[tt] = zz; }
            if (producer) {
                h8 A;
                if (q < 2) A = cvt8v(xb + (size_t)(16 * c + nl) * NI + 8 * q);
                else { h8 zz = {}; A = zz; }
#pragma unroll
                for (int tt = 0; tt < 12; tt++) accs[tt] = mfma16(A, Bf1[tt], accs[tt]);
            } else {
                if (lane == 0) wait_flag(fb + c);
                const _Float16* yr = yb + (size_t)(16 * c + nl) * H;
                h8 A[4];
#pragma unroll
                for (int kc = 0; kc < 4; kc++)
                    A[kc] = load_y0_h8(yr + 32 * kc + 8 * q);
#pragma unroll
                for (int kc = 0; kc < 4; kc++)
#pragma unroll
                    for (int tt = 0; tt < 12; tt++)
                        accs[tt] = mfma16(A[kc], Bf4[tt][kc], accs[tt]);
            }
            float* gp = &sGi[c & 1][0][0][0];
#pragma unroll
            for (int tt = 0; tt < 12; tt++) {
                const int n = 16 * (hw * 12 + tt) + nl;
                const int g = n >> 7, jj = n & 127;
#pragma unroll
                for (int r = 0; r < 4; r++)
                    gp[((4 * q + r) * 3 + g) * GIP + jj] = accs[tt][r] + bias[tt];
            }
            publish(&sGiDone[hw], c + 1);   // release: orders the LDS writes
        }
        // tail: flush chunks NCH-2, NCH-1
        for (int k = NCH - 2; k < NCH; k++) {
            poll_ge(&sCnt[0], 16 * (k + 1));
            poll_ge(&sCnt[1], 16 * (k + 1));
            const uint2* src = (const uint2*)&sO[k & 1][0][0];
#pragma unroll
            for (int e = 0; e < 4; e++) {
                const int idx = hw * 256 + 64 * e + lane;
                const uint2 v = src[idx];
                if (producer)
                    store_y0((char*)(yb + (size_t)k * CH * H) + 8 * idx, v);
                else
                    *(uint2*)((char*)(yb + (size_t)k * CH * H) + 8 * idx) = v;
            }
            if (producer) {
                publish(&sFlush[hw], k + 1);
                if (hw == 0) {
                    poll_ge(&sFlush[1], k + 1);
                    if (lane == 0) post_flag(fb + k);
                }
            }
        }
    }
}

// ---------------------------------------------------------------------------
// MFMA MLP head. 512 blocks x 256 threads (4 independent waves, no barriers).
// ---------------------------------------------------------------------------
__global__ __launch_bounds__(256, 2)
void head_mfma(const _Float16* __restrict__ h1, const float* __restrict__ x,
               const float* __restrict__ w1, const float* __restrict__ b1,
               const float* __restrict__ w2, const float* __restrict__ b2,
               float* __restrict__ inc)
{
    const int wave = threadIdx.x >> 6;
    const int lane = threadIdx.x & 63;
    const int nl   = lane & 15;
    const int q    = lane >> 4;

    h8 Bf[4][5];
    float b1v[4], w2v[4];
#pragma unroll
    for (int t = 0; t < 4; t++) {
        const int n = 16 * t + nl;
        const float* wr = w1 + (size_t)n * F;
#pragma unroll
        for (int c = 0; c < 4; c++)
            Bf[t][c] = cvt8v(wr + 32 * c + 8 * q);
        if (q < 2) Bf[t][4] = cvt8v(wr + 128 + 8 * q);
        else { h8 z = {};
               Bf[t][4] = z; }
        b1v[t] = b1[n];
        w2v[t] = w2[n];
    }
    const float b2v = b2[0];

    const int gw = blockIdx.x * 4 + wave;

    for (int it = 0; it < 8; it++) {
        const int row0 = (gw * 8 + it) * 16;
        const int rm   = row0 + nl;

        const _Float16* hp = h1 + (size_t)rm * H;
        h8 A0 = *(const h8*)(hp + 8 * q);
        h8 A1 = *(const h8*)(hp + 32 + 8 * q);
        h8 A2 = *(const h8*)(hp + 64 + 8 * q);
        h8 A3 = *(const h8*)(hp + 96 + 8 * q);
        h8 A4;
        if (q < 2) A4 = cvt8v(x + (size_t)rm * NI + 8 * q);
        else { h8 z = {}; A4 = z; }

        f4v acc0 = {0.f,0.f,0.f,0.f}, acc1 = {0.f,0.f,0.f,0.f};
        f4v acc2 = {0.f,0.f,0.f,0.f}, acc3 = {0.f,0.f,0.f,0.f};
        acc0 = mfma16(A0, Bf[0][0], acc0); acc1 = mfma16(A0, Bf[1][0], acc1);
        acc2 = mfma16(A0, Bf[2][0], acc2); acc3 = mfma16(A0, Bf[3][0], acc3);
        acc0 = mfma16(A1, Bf[0][1], acc0); acc1 = mfma16(A1, Bf[1][1], acc1);
        acc2 = mfma16(A1, Bf[2][1], acc2); acc3 = mfma16(A1, Bf[3][1], acc3);
        acc0 = mfma16(A2, Bf[0][2], acc0); acc1 = mfma16(A2, Bf[1][2], acc1);
        acc2 = mfma16(A2, Bf[2][2], acc2); acc3 = mfma16(A2, Bf[3][2], acc3);
        acc0 = mfma16(A3, Bf[0][3], acc0); acc1 = mfma16(A3, Bf[1][3], acc1);
        acc2 = mfma16(A3, Bf[2][3], acc2); acc3 = mfma16(A3, Bf[3][3], acc3);
        acc0 = mfma16(A4, Bf[0][4], acc0); acc1 = mfma16(A4, Bf[1][4], acc1);
        acc2 = mfma16(A4, Bf[2][4], acc2); acc3 = mfma16(A4, Bf[3][4], acc3);

        float rs[4];
#pragma unroll
        for (int r = 0; r < 4; r++) {
            rs[r] = fmaxf(acc0[r] + b1v[0], 0.f) * w2v[0]
                  + fmaxf(acc1[r] + b1v[1], 0.f) * w2v[1]
                  + fmaxf(acc2[r] + b1v[2], 0.f) * w2v[2]
                  + fmaxf(acc3[r] + b1v[3], 0.f) * w2v[3];
        }
#pragma unroll
        for (int off = 1; off < 16; off <<= 1) {
#pragma unroll
            for (int r = 0; r < 4; r++)
                rs[r] += __shfl_xor(rs[r], off, 64);
        }
        if (nl == 0) {
            float4 o;
            o.x = tanh_fast(rs[0] + b2v) * 0.125f;
            o.y = tanh_fast(rs[1] + b2v) * 0.125f;
            o.z = tanh_fast(rs[2] + b2v) * 0.125f;
            o.w = tanh_fast(rs[3] + b2v) * 0.125f;
            *(float4*)(inc + row0 + 4 * q) = o;
        }
    }
}

// ---------------------------------------------------------------------------
// Inclusive cumsum over S per batch + initial offset. One block per batch.
// ---------------------------------------------------------------------------
__global__ __launch_bounds__(256)
void cumsum_kernel(const float* __restrict__ inc, const float* __restrict__ init,
                   float* __restrict__ out)
{
    __shared__ float sW[4];
    const int b = blockIdx.x;
    const int tid = threadIdx.x;
    const int lane = tid & 63;
    const int wid = tid >> 6;

    const float* ib = inc + (size_t)b * S;
    float v[16];
#pragma unroll
    for (int i = 0; i < 16; i++) v[i] = ib[tid * 16 + i];

    float run = 0.f;
#pragma unroll
    for (int i = 0; i < 16; i++) { run += v[i]; v[i] = run; }

    float t = run;
#pragma unroll
    for (int off = 1; off < 64; off <<= 1) {
        float u = __shfl_up(t, off, 64);
        if (lane >= off) t += u;
    }
    const float excl = t - run;
    if (lane == 63) sW[wid] = t;
    __syncthreads();

    float wo = 0.f;
#pragma unroll
    for (int w = 0; w < 4; w++) if (w < wid) wo += sW[w];

    const float prefix = wo + excl + init[0];
    float* ob = out + (size_t)b * S;
#pragma unroll
    for (int i = 0; i < 16; i++) ob[tid * 16 + i] = prefix + v[i];
}

// ---------------------------------------------------------------------------
extern "C" void kernel_launch(void* const* d_in, const int* in_sizes, int n_in,
                              void* d_out, int out_size, void* d_ws, size_t ws_size,
                              hipStream_t stream)
{
    (void)in_sizes; (void)n_in; (void)out_size; (void)ws_size;
    const float* x     = (const float*)d_in[0];
    const float* w_ih0 = (const float*)d_in[1];
    const float* w_hh0 = (const float*)d_in[2];
    const float* b_ih0 = (const float*)d_in[3];
    const float* b_hh0 = (const float*)d_in[4];
    const float* w_ih1 = (const float*)d_in[5];
    const float* w_hh1 = (const float*)d_in[6];
    const float* b_ih1 = (const float*)d_in[7];
    const float* b_hh1 = (const float*)d_in[8];
    const float* w1    = (const float*)d_in[9];
    const float* b1    = (const float*)d_in[10];
    const float* w2    = (const float*)d_in[11];
    const float* b2    = (const float*)d_in[12];
    const float* init  = (const float*)d_in[13];
    float* out = (float*)d_out;

    _Float16* hbuf = (_Float16*)d_ws;                                   // 64 MB fp16
    float* incbuf  = (float*)((char*)d_ws + (size_t)B * S * H * 2);     // 1 MB
    int* flags     = (int*)((char*)d_ws + (size_t)B * S * H * 2
                                        + (size_t)B * S * 4);           // 64 KB

    hipMemsetAsync(flags, 0, (size_t)B * NCH * sizeof(int), stream);

    hipLaunchKernelGGL(gru_poll, dim3(2 * B), dim3(256), 0, stream,
                       x, w_ih0, w_hh0, b_ih0, b_hh0,
                       w_ih1, w_hh1, b_ih1, b_hh1, hbuf, flags);
    hipLaunchKernelGGL(head_mfma, dim3(512), dim3(256), 0, stream,
                       hbuf, x, w1, b1, w2, b2, incbuf);
    hipLaunchKernelGGL(cumsum_kernel, dim3(B), dim3(256), 0, stream,
                       incbuf, init, out);
}